// Round 5
// baseline (486.957 us; speedup 1.0000x reference)
//
#include <hip/hip_runtime.h>
#include <math.h>

// Problem sizes
constexpr int NPTS = 8192;
constexpr int DIM  = 512;
constexpr int KC   = 8;    // clusters
constexpr int NNB  = 5;    // neighbors

// Output layout (floats)
constexpr int OFF_ENC    = 0;
constexpr int OFF_ASSIGN = NPTS * 32;                 // 262144
constexpr int OFF_KNN    = OFF_ASSIGN + NPTS * KC;    // 327680
constexpr int OFF_STATS  = OFF_KNN + NPTS * NNB;      // 368640
constexpr int OFF_LOSS   = OFF_STATS + NPTS * 3;      // 393216 (loss, intra, inter)

// Workspace layout (float offsets)
constexpr int WS_CNORM = 0;            // 8
constexpr int WS_INTER = 8;            // 1
constexpr int WS_XX    = 16;           // 8192 row norms
constexpr int WS_INTRA = 16 + NPTS;    // 512 block partials
constexpr int WS_CAND  = 16 + NPTS + 512; // float2[NPTS][40] candidates (key, idx)
constexpr size_t XB_OFF = 4u << 20;    // byte offset of packed bf16 copy of x (8 MB)

typedef short bf16x8 __attribute__((ext_vector_type(8)));
typedef float f32x16 __attribute__((ext_vector_type(16)));

__device__ __forceinline__ float waveAllSum(float v) {
#pragma unroll
  for (int m = 1; m < 64; m <<= 1) v += __shfl_xor(v, m);
  return v;
}
__device__ __forceinline__ float waveAllMax(float v) {
#pragma unroll
  for (int m = 1; m < 64; m <<= 1) v = fmaxf(v, __shfl_xor(v, m));
  return v;
}

__device__ __forceinline__ unsigned short f2bf(float f) {
  unsigned u = __float_as_uint(f);
  unsigned r = (u + 0x7FFFu + ((u >> 16) & 1u)) >> 16;  // RNE
  return (unsigned short)r;
}

// async global(16B/lane) -> LDS, linear dest (wave-uniform base + lane*16)
__device__ __forceinline__ void gload16(const void* g, void* lds) {
  __builtin_amdgcn_global_load_lds(
      (const __attribute__((address_space(1))) unsigned int*)(unsigned long long)g,
      (__attribute__((address_space(3))) unsigned int*)(unsigned)(unsigned long long)lds,
      16, 0, 0);
}

// ---------------- k_init: center norms + inter-cluster distance ----------------
__global__ void k_init(const float* __restrict__ cc, float* __restrict__ ws) {
  int t = threadIdx.x;
  if (t < KC) {
    float s = 0.f;
    for (int j = 0; j < DIM; j++) { float v = cc[t * DIM + j]; s = fmaf(v, v, s); }
    ws[WS_CNORM + t] = s;
  }
  __syncthreads();
  int i = t >> 3, j = t & 7;
  float dot = 0.f;
  for (int u = 0; u < DIM; u++) dot = fmaf(cc[i * DIM + u], cc[j * DIM + u], dot);
  float d2 = ws[WS_CNORM + i] + ws[WS_CNORM + j] - 2.f * dot;
  float d = d2 > 0.f ? sqrtf(d2) : 0.f;
  float v = (i != j) ? d : 0.f;
  v = waveAllSum(v);
  if (t == 0) ws[WS_INTER] = v / 56.f;
}

// ---------------- k_stats: row stats + soft assignment + intra partials --------
__global__ __launch_bounds__(256) void k_stats(
    const float* __restrict__ x, const float* __restrict__ cc,
    const float* __restrict__ temp, const float* __restrict__ cw,
    float* __restrict__ out, float* __restrict__ ws) {
  __shared__ __align__(16) float Cs[KC * DIM];
  __shared__ float cns[KC], cwS[KC];
  __shared__ float intraS[4];
  int tid = threadIdx.x;
  for (int i = tid * 4; i < KC * DIM; i += 1024)
    *(float4*)&Cs[i] = *(const float4*)&cc[i];
  if (tid < KC) { cns[tid] = ws[WS_CNORM + tid]; cwS[tid] = cw[tid]; }
  __syncthreads();
  float T = temp[0];
  int w = tid >> 6, l = tid & 63;
  float intra_acc = 0.f;
  for (int q = 0; q < 4; q++) {
    int row = blockIdx.x * 16 + w * 4 + q;
    float4 v0 = *(const float4*)&x[row * DIM + l * 4];
    float4 v1 = *(const float4*)&x[row * DIM + 256 + l * 4];
    float xv[8] = {v0.x, v0.y, v0.z, v0.w, v1.x, v1.y, v1.z, v1.w};
    float s1 = 0.f, s2 = 0.f, mx = -3e38f;
#pragma unroll
    for (int u = 0; u < 8; u++) { s1 += xv[u]; s2 = fmaf(xv[u], xv[u], s2); mx = fmaxf(mx, xv[u]); }
    s1 = waveAllSum(s1); s2 = waveAllSum(s2); mx = waveAllMax(mx);
    float e = 0.f, ex = 0.f;
#pragma unroll
    for (int u = 0; u < 8; u++) { float p = expf(xv[u] - mx); e += p; ex = fmaf(xv[u], p, ex); }
    e = waveAllSum(e); ex = waveAllSum(ex);
    float dk[KC];
#pragma unroll
    for (int k = 0; k < KC; k++) {
      float4 c0 = *(const float4*)&Cs[k * DIM + l * 4];
      float4 c1 = *(const float4*)&Cs[k * DIM + 256 + l * 4];
      float d = v0.x * c0.x + v0.y * c0.y + v0.z * c0.z + v0.w * c0.w
              + v1.x * c1.x + v1.y * c1.y + v1.z * c1.z + v1.w * c1.w;
      dk[k] = waveAllSum(d);
    }
    float mu = s1 / 512.f;
    float var = (s2 - 512.f * mu * mu) / 511.f;
    if (var < 0.f) var = 0.f;
    float sd = sqrtf(var) + 1e-8f;
    float lse = mx + logf(e);
    float ent = lse - ex / e;
    float dcv[KC], am = -3e38f;
#pragma unroll
    for (int k = 0; k < KC; k++) {
      float d2 = s2 + cns[k] - 2.f * dk[k];
      dcv[k] = d2 > 0.f ? sqrtf(d2) : 0.f;
      am = fmaxf(am, -dcv[k] / T);
    }
    float psum = 0.f, pv[KC];
#pragma unroll
    for (int k = 0; k < KC; k++) { pv[k] = expf(-dcv[k] / T - am); psum += pv[k]; }
    float il = 0.f, asg[KC];
#pragma unroll
    for (int k = 0; k < KC; k++) { asg[k] = pv[k] / psum * cwS[k]; il = fmaf(dcv[k], asg[k], il); }
    intra_acc += il;
    if (l == 0) {
      ws[WS_XX + row] = s2;
      out[OFF_STATS + row * 3 + 0] = mu;
      out[OFF_STATS + row * 3 + 1] = sd;
      out[OFF_STATS + row * 3 + 2] = ent;
#pragma unroll
      for (int k = 0; k < KC; k++) out[OFF_ASSIGN + row * KC + k] = asg[k];
    }
  }
  if (l == 0) intraS[w] = intra_acc;
  __syncthreads();
  if (tid == 0)
    ws[WS_INTRA + blockIdx.x] = intraS[0] + intraS[1] + intraS[2] + intraS[3];
}

// ---------------- k_final: scalar loss outputs ----------------
__global__ void k_final(float* __restrict__ out, const float* __restrict__ ws) {
  __shared__ float ps[4];
  int t = threadIdx.x;
  float v = ws[WS_INTRA + t] + ws[WS_INTRA + t + 256];
  v = waveAllSum(v);
  if ((t & 63) == 0) ps[t >> 6] = v;
  __syncthreads();
  if (t == 0) {
    float intra = (ps[0] + ps[1] + ps[2] + ps[3]) / (8192.f * 8.f);
    float inter = ws[WS_INTER];
    out[OFF_LOSS + 0] = intra - 0.1f * inter;
    out[OFF_LOSS + 1] = intra;
    out[OFF_LOSS + 2] = inter;
  }
}

// ---------------- k_pack: x f32 -> bf16 packed into MFMA fragment layout ------
__global__ __launch_bounds__(256) void k_pack(const float* __restrict__ x,
                                              unsigned short* __restrict__ xp) {
  int t = blockIdx.x * 256 + threadIdx.x;   // one thread per 16B unit-lane
  int lane = t & 63;
  int kk = (t >> 6) & 31;
  int grp = t >> 11;
  int point = grp * 32 + (lane & 31);
  int k0 = kk * 16 + (lane >> 5) * 8;
  const float* src = x + point * DIM + k0;
  float4 v0 = *(const float4*)src;
  float4 v1 = *(const float4*)(src + 4);
  bf16x8 o;
  o[0] = (short)f2bf(v0.x); o[1] = (short)f2bf(v0.y);
  o[2] = (short)f2bf(v0.z); o[3] = (short)f2bf(v0.w);
  o[4] = (short)f2bf(v1.x); o[5] = (short)f2bf(v1.y);
  o[6] = (short)f2bf(v1.z); o[7] = (short)f2bf(v1.w);
  *(bf16x8*)(xp + (size_t)t * 8) = o;
}

// ---------------- k_gemm3: barrier-free MFMA + clean-d2 top-5 (no noise) ------
// grid (128, 4) XCD-swizzled; block = 512 threads (8 waves), 64 rows x 2048 cols.
// Rows (64KB) staged ONCE via gload16. Cols stream global->VGPR. No K barriers.
// Swapped operands -> row in lane, 16 cols in regs. Selection key: clean
// partial p = xc - 2*dot (xr const per row, added at candp write); noise is
// applied only to the ~20 finalists in k_merge (1e-6-scale => output diff <1e-5).

#define INS5(P, KEY, IDX)                                                        \
  { float a_ = (KEY); int b_ = (IDX);                                            \
    if (a_ < k##P##0) { float t_=k##P##0; k##P##0=a_; a_=t_; int u_=i##P##0; i##P##0=b_; b_=u_; } \
    if (a_ < k##P##1) { float t_=k##P##1; k##P##1=a_; a_=t_; int u_=i##P##1; i##P##1=b_; b_=u_; } \
    if (a_ < k##P##2) { float t_=k##P##2; k##P##2=a_; a_=t_; int u_=i##P##2; i##P##2=b_; b_=u_; } \
    if (a_ < k##P##3) { float t_=k##P##3; k##P##3=a_; a_=t_; int u_=i##P##3; i##P##3=b_; b_=u_; } \
    if (a_ < k##P##4) { float t_=k##P##4; k##P##4=a_; a_=t_; int u_=i##P##4; i##P##4=b_; b_=u_; } }

__global__ __launch_bounds__(512, 4) void k_gemm3(
    const unsigned short* __restrict__ xp, float* __restrict__ ws) {
  __shared__ __align__(16) char SMEM[65536];
  __shared__ __align__(16) float xxcS[2048];
  const int tid = threadIdx.x;
  const int l = tid & 63, w = tid >> 6;
  const int lh = l >> 5;

  // XCD-chunked swizzle: XCD k owns works k*64..k*64+63 (one col chunk hot/L2)
  const int flat = blockIdx.y * 128 + blockIdx.x;
  const int work = (flat & 7) * 64 + (flat >> 3);
  const int rb = work & 127;          // row-block (64 rows)
  const int cchunk = work >> 7;       // col chunk (2048 cols)
  const int rowbase = rb * 64;
  const int colbase = cchunk * 2048;

  const float* xxg = ws + WS_XX;
  float2* candp = (float2*)(ws + WS_CAND);

  // ---- stage 64 rows x 512 k once: 64 x 1KB units, wave w stages units w*8..w*8+7
  {
    const int rg0 = rb * 2;
#pragma unroll
    for (int i = 0; i < 8; i++) {
      const int u = w * 8 + i;                              // u = g*32 + kk
      const size_t src = ((size_t)(rg0 + (u >> 5)) * 32 + (u & 31)) * 512 + l * 8;
      gload16(xp + src, SMEM + u * 1024);
    }
  }
  for (int i = tid; i < 2048; i += 512) xxcS[i] = xxg[colbase + i];

  const int rowA = rowbase + (l & 31);
  const int rowB = rowA + 32;

  float ka0=3e38f,ka1=3e38f,ka2=3e38f,ka3=3e38f,ka4=3e38f;
  float kb0=3e38f,kb1=3e38f,kb2=3e38f,kb3=3e38f,kb4=3e38f;
  int   ia0=-1,ia1=-1,ia2=-1,ia3=-1,ia4=-1;
  int   ib0=-1,ib1=-1,ib2=-1,ib3=-1,ib4=-1;

  __syncthreads();  // rows + col-norms resident; only barrier before merge

  for (int ct = 0; ct < 8; ct++) {
    const int cgrp = cchunk * 64 + ct * 8 + w;     // this wave's 32-col group
    const unsigned short* colp = xp + (size_t)cgrp * 16384 + l * 8;

    f32x16 a0, a1;
#pragma unroll
    for (int r = 0; r < 16; r++) { a0[r] = 0.f; a1[r] = 0.f; }

#pragma unroll
    for (int kk = 0; kk < 32; kk++) {
      bf16x8 cf = *(const bf16x8*)(colp + kk * 512);
      const char* rp = SMEM + kk * 1024 + l * 16;
      bf16x8 r0 = *(const bf16x8*)rp;
      bf16x8 r1 = *(const bf16x8*)(rp + 32768);
      a0 = __builtin_amdgcn_mfma_f32_32x32x16_bf16(cf, r0, a0, 0, 0, 0);
      a1 = __builtin_amdgcn_mfma_f32_32x32x16_bf16(cf, r1, a1, 0, 0, 0);
    }

    // epilogue: lane-local clean-d2 top-5 (partial domain), pure registers
    const int coltL = ct * 256 + w * 32;             // local col within chunk
    const int colt  = colbase + coltL;
    float xq[16];
#pragma unroll
    for (int g = 0; g < 4; g++) {
      float4 t0 = *(const float4*)&xxcS[coltL + 8 * g + 4 * lh];
      xq[4*g+0]=t0.x; xq[4*g+1]=t0.y; xq[4*g+2]=t0.z; xq[4*g+3]=t0.w;
    }
#pragma unroll
    for (int r = 0; r < 16; r++) {
      const int cOff = (r & 3) + 8 * (r >> 2) + 4 * lh;
      const int c = colt + cOff;
      const float pa = xq[r] - 2.0f * a0[r];
      if (pa < ka4 && c != rowA) INS5(a, pa, c)
      const float pb = xq[r] - 2.0f * a1[r];
      if (pb < kb4 && c != rowB) INS5(b, pb, c)
    }
  }

  // ---- lane^32 merge (lanes l, l^32 share the same two rows) ----
  float MA[5], MB_[5]; int JA[5], JB_[5];
  {
    float m0=ka0,m1=ka1,m2=ka2,m3=ka3,m4=ka4;
    int   n0=ia0,n1=ia1,n2=ia2,n3=ia3,n4=ia4;
#pragma unroll
    for (int s = 0; s < 5; s++) {
      float ok = __shfl_xor(m0, 32); int oi = __shfl_xor(n0, 32);
      bool take = (m0 < ok) || (m0 == ok && (unsigned)n0 <= (unsigned)oi);
      MA[s] = take ? m0 : ok; JA[s] = take ? n0 : oi;
      if (take) { m0=m1;n0=n1; m1=m2;n1=n2; m2=m3;n2=n3; m3=m4;n3=n4; m4=3e38f;n4=-1; }
    }
  }
  {
    float m0=kb0,m1=kb1,m2=kb2,m3=kb3,m4=kb4;
    int   n0=ib0,n1=ib1,n2=ib2,n3=ib3,n4=ib4;
#pragma unroll
    for (int s = 0; s < 5; s++) {
      float ok = __shfl_xor(m0, 32); int oi = __shfl_xor(n0, 32);
      bool take = (m0 < ok) || (m0 == ok && (unsigned)n0 <= (unsigned)oi);
      MB_[s] = take ? m0 : ok; JB_[s] = take ? n0 : oi;
      if (take) { m0=m1;n0=n1; m1=m2;n1=n2; m2=m3;n2=n3; m3=m4;n3=n4; m4=3e38f;n4=-1; }
    }
  }

  // ---- cross-wave merge: 16 lists/row -> 5; write d2 = partial + xr ----
  __syncthreads();  // done reading row tile
  float2* mrg = (float2*)SMEM;  // [64 rows][8 waves][5]
#pragma unroll
  for (int s = 0; s < 5; s++) {
    float2 e = (l < 32) ? make_float2(MA[s], __int_as_float(JA[s]))
                        : make_float2(MB_[s], __int_as_float(JB_[s]));
    mrg[(l * 8 + w) * 5 + s] = e;
  }
  __syncthreads();
  if (l < 8) {
    const int row = w * 8 + l;   // 8 waves x 8 lanes cover 64 rows
    const float xr = xxg[rowbase + row];
    float2 h[8]; int p[8];
#pragma unroll
    for (int j = 0; j < 8; j++) { h[j] = mrg[(row * 8 + j) * 5]; p[j] = 0; }
    const size_t base = (size_t)(rowbase + row) * 40 + cchunk * 5;
#pragma unroll
    for (int s = 0; s < 5; s++) {
      int bj = 0; float bk = h[0].x; int bi = __float_as_int(h[0].y);
#pragma unroll
      for (int j = 1; j < 8; j++) {
        float kj = h[j].x; int ij = __float_as_int(h[j].y);
        if (kj < bk || (kj == bk && (unsigned)ij < (unsigned)bi)) { bk = kj; bi = ij; bj = j; }
      }
      candp[base + s] = make_float2(fmaxf(bk + xr, 0.f), __int_as_float(bi));
      p[bj]++;
      h[bj] = (p[bj] < 5) ? mrg[(row * 8 + bj) * 5 + p[bj]]
                          : make_float2(3e38f, __int_as_float(-1));
    }
  }
}

// ---------------- k_gemm (fallback, fp32 VALU): unchanged ----------------
__global__ __launch_bounds__(256, 2) void k_gemm(
    const float* __restrict__ x, const float* __restrict__ noise,
    float* __restrict__ ws) {
  __shared__ __align__(16) float As[16][132];
  __shared__ __align__(16) float Bs[16][132];
  __shared__ float xxc[1024];
  const int tid = threadIdx.x;
  const int tx = tid & 7, ty = tid >> 3;
  const int rowbase = blockIdx.x * 128;
  const int colbase = blockIdx.y * 1024;
  const float* xxg = ws + WS_XX;

  for (int i = tid; i < 1024; i += 256) xxc[i] = xxg[colbase + i];
  float xxr[4];
#pragma unroll
  for (int r = 0; r < 4; r++) xxr[r] = xxg[rowbase + ty * 4 + r];

  float k5[4][5]; int i5[4][5];
#pragma unroll
  for (int r = 0; r < 4; r++)
#pragma unroll
    for (int s = 0; s < 5; s++) { k5[r][s] = 3e38f; i5[r][s] = -1; }

  const int rlo = tid >> 2, kq = tid & 3;

  for (int ct = 0; ct < 8; ct++) {
    const int colt = colbase + ct * 128;
    float acc[4][16];
#pragma unroll
    for (int r = 0; r < 4; r++)
#pragma unroll
      for (int c = 0; c < 16; c++) acc[r][c] = 0.f;

    for (int kk = 0; kk < 512; kk += 16) {
      __syncthreads();
      float4 a0 = *(const float4*)&x[(rowbase + rlo) * DIM + kk + kq * 4];
      float4 a1 = *(const float4*)&x[(rowbase + rlo + 64) * DIM + kk + kq * 4];
      float4 b0 = *(const float4*)&x[(colt + rlo) * DIM + kk + kq * 4];
      float4 b1 = *(const float4*)&x[(colt + rlo + 64) * DIM + kk + kq * 4];
      As[kq * 4 + 0][rlo] = a0.x; As[kq * 4 + 1][rlo] = a0.y;
      As[kq * 4 + 2][rlo] = a0.z; As[kq * 4 + 3][rlo] = a0.w;
      As[kq * 4 + 0][rlo + 64] = a1.x; As[kq * 4 + 1][rlo + 64] = a1.y;
      As[kq * 4 + 2][rlo + 64] = a1.z; As[kq * 4 + 3][rlo + 64] = a1.w;
      Bs[kq * 4 + 0][rlo] = b0.x; Bs[kq * 4 + 1][rlo] = b0.y;
      Bs[kq * 4 + 2][rlo] = b0.z; Bs[kq * 4 + 3][rlo] = b0.w;
      Bs[kq * 4 + 0][rlo + 64] = b1.x; Bs[kq * 4 + 1][rlo + 64] = b1.y;
      Bs[kq * 4 + 2][rlo + 64] = b1.z; Bs[kq * 4 + 3][rlo + 64] = b1.w;
      __syncthreads();
#pragma unroll
      for (int k = 0; k < 16; k++) {
        float4 av = *(const float4*)&As[k][ty * 4];
        float a_[4] = {av.x, av.y, av.z, av.w};
#pragma unroll
        for (int j = 0; j < 4; j++) {
          float4 bv = *(const float4*)&Bs[k][tx * 4 + j * 32];
          float b_[4] = {bv.x, bv.y, bv.z, bv.w};
#pragma unroll
          for (int rr = 0; rr < 4; rr++)
#pragma unroll
            for (int uu = 0; uu < 4; uu++)
              acc[rr][j * 4 + uu] = fmaf(a_[rr], b_[uu], acc[rr][j * 4 + uu]);
        }
      }
    }
#pragma unroll
    for (int r = 0; r < 4; r++) {
      const int row = rowbase + ty * 4 + r;
#pragma unroll
      for (int j = 0; j < 4; j++) {
        const int cl = tx * 4 + j * 32;
        const int col = colt + cl;
        const float4 nz = *(const float4*)&noise[(size_t)row * NPTS + col];
        float nzv[4] = {nz.x, nz.y, nz.z, nz.w};
#pragma unroll
        for (int u = 0; u < 4; u++) {
          float d2 = xxr[r] + xxc[ct * 128 + cl + u] - 2.f * acc[r][j * 4 + u];
          float d = d2 > 0.f ? sqrtf(d2) : 0.f;
          float key = d + 1e-6f * nzv[u];
          int c = col + u;
          if (c != row && key < k5[r][4]) {
            float a = key; int b = c;
#pragma unroll
            for (int s = 0; s < 5; s++) {
              if (a < k5[r][s]) {
                float tf = k5[r][s]; k5[r][s] = a; a = tf;
                int ti = i5[r][s]; i5[r][s] = b; b = ti;
              }
            }
          }
        }
      }
    }
  }

#pragma unroll
  for (int r = 0; r < 4; r++) {
    const int row = rowbase + ty * 4 + r;
    float lk[5]; int li[5];
#pragma unroll
    for (int s = 0; s < 5; s++) { lk[s] = k5[r][s]; li[s] = i5[r][s]; }
#pragma unroll
    for (int s = 0; s < 5; s++) {
      float wk = lk[0]; int wi = li[0];
#pragma unroll
      for (int m = 1; m < 8; m <<= 1) {
        float k2 = __shfl_xor(wk, m); int i2 = __shfl_xor(wi, m);
        if (k2 < wk || (k2 == wk && (unsigned)i2 < (unsigned)wi)) { wk = k2; wi = i2; }
      }
      if (li[0] == wi && lk[0] == wk) {
        lk[0] = lk[1]; li[0] = li[1];
        lk[1] = lk[2]; li[1] = li[2];
        lk[2] = lk[3]; li[2] = li[3];
        lk[3] = lk[4]; li[3] = li[4];
        lk[4] = 3e38f; li[4] = -1;
      }
      if (tx == 0) {
        float2* cand = (float2*)(ws + WS_CAND);
        cand[(size_t)row * 40 + blockIdx.y * 5 + s] = make_float2(wk, __int_as_float(wi));
      }
    }
  }
}

// ---------------- k_merge: final top-5 + feats + MLP ----------------
// mode 0: cand.x is noisy key (fallback). mode 1: cand.x is clean d2; build
// noisy key = sqrt(d2) + 1e-6*noise here (20 scalar loads/row).
__global__ __launch_bounds__(256) void k_merge(
    const float* __restrict__ noise, const float* __restrict__ w1,
    const float* __restrict__ b1, const float* __restrict__ w2,
    const float* __restrict__ b2, float* __restrict__ out,
    const float* __restrict__ ws, int nslots, int mode) {
  __shared__ float w1s[16 * 64];
  __shared__ float b1s[64];
  __shared__ float w2s[64 * 32];
  __shared__ float b2s[32];
  __shared__ float featsS[4][16];
  __shared__ float hS[4][64];
  int tid = threadIdx.x;
  for (int i = tid; i < 1024; i += 256) w1s[i] = w1[i];
  for (int i = tid; i < 2048; i += 256) w2s[i] = w2[i];
  if (tid < 64) b1s[tid] = b1[tid];
  if (tid < 32) b2s[tid] = b2[tid];
  __syncthreads();
  int w = tid >> 6, l = tid & 63;
  const float2* cand = (const float2*)(ws + WS_CAND);
  for (int q = 0; q < 8; q++) {
    int row = blockIdx.x * 32 + w * 8 + q;
    float mk = 3e38f; int mi = -1;
    if (l < nslots) {
      float2 c = cand[(size_t)row * 40 + l];
      mi = __float_as_int(c.y);
      if (mode) {
        float d = sqrtf(c.x);
        mk = fmaf(1e-6f, noise[(size_t)row * NPTS + mi], d);
      } else {
        mk = c.x;
      }
    }
#pragma unroll
    for (int s = 0; s < 5; s++) {
      float wk = mk; int wi = mi;
#pragma unroll
      for (int m = 1; m < 64; m <<= 1) {
        float k2 = __shfl_xor(wk, m); int i2 = __shfl_xor(wi, m);
        if (k2 < wk || (k2 == wk && (unsigned)i2 < (unsigned)wi)) { wk = k2; wi = i2; }
      }
      if (mi == wi && mk == wk) mk = 3e38f;  // remove winner from my slot
      if (l == s) {
        float nv = noise[(size_t)row * NPTS + wi];
        float dclean = wk - 1e-6f * nv;
        out[OFF_KNN + row * NNB + s] = dclean;
        featsS[w][8 + s] = dclean;
      }
    }
    if (l < 8) featsS[w][l] = out[OFF_ASSIGN + row * KC + l];
    if (l >= 13 && l < 16) featsS[w][l] = out[OFF_STATS + row * 3 + (l - 13)];
    __syncthreads();
    float h = b1s[l];
#pragma unroll
    for (int i = 0; i < 16; i++) h = fmaf(featsS[w][i], w1s[i * 64 + l], h);
    hS[w][l] = fmaxf(h, 0.f);
    __syncthreads();
    if (l < 32) {
      float e = b2s[l];
#pragma unroll
      for (int i = 0; i < 64; i++) e = fmaf(hS[w][i], w2s[i * 32 + l], e);
      out[OFF_ENC + row * 32 + l] = e;
    }
    __syncthreads();
  }
}

extern "C" void kernel_launch(void* const* d_in, const int* in_sizes, int n_in,
                              void* d_out, int out_size, void* d_ws, size_t ws_size,
                              hipStream_t stream) {
  const float* x     = (const float*)d_in[0];
  const float* noise = (const float*)d_in[1];
  const float* cc    = (const float*)d_in[2];
  const float* w1    = (const float*)d_in[3];
  const float* b1    = (const float*)d_in[4];
  const float* w2    = (const float*)d_in[5];
  const float* b2    = (const float*)d_in[6];
  const float* temp  = (const float*)d_in[7];
  const float* cw    = (const float*)d_in[8];
  float* out = (float*)d_out;
  float* ws  = (float*)d_ws;

  const size_t need = XB_OFF + (size_t)NPTS * DIM * 2;  // 12.4 MB
  const bool fast = ws_size >= need;

  hipLaunchKernelGGL(k_init,  dim3(1),   dim3(64),  0, stream, cc, ws);
  hipLaunchKernelGGL(k_stats, dim3(512), dim3(256), 0, stream, x, cc, temp, cw, out, ws);
  hipLaunchKernelGGL(k_final, dim3(1),   dim3(256), 0, stream, out, ws);
  if (fast) {
    unsigned short* xp = (unsigned short*)((char*)d_ws + XB_OFF);
    hipLaunchKernelGGL(k_pack,  dim3(2048),   dim3(256), 0, stream, x, xp);
    hipLaunchKernelGGL(k_gemm3, dim3(128, 4), dim3(512), 0, stream, xp, ws);
    hipLaunchKernelGGL(k_merge, dim3(256), dim3(256), 0, stream, noise, w1, b1, w2, b2, out, ws, 20, 1);
  } else {
    hipLaunchKernelGGL(k_gemm,  dim3(64, 8), dim3(256), 0, stream, x, noise, ws);
    hipLaunchKernelGGL(k_merge, dim3(256), dim3(256), 0, stream, noise, w1, b1, w2, b2, out, ws, 40, 0);
  }
}

// Round 6
// 210.612 us; speedup vs baseline: 2.3121x; 2.3121x over previous
//
#include <hip/hip_runtime.h>
#include <math.h>

// Problem sizes
constexpr int NPTS = 8192;
constexpr int DIM  = 512;
constexpr int KC   = 8;    // clusters
constexpr int NNB  = 5;    // neighbors

// Output layout (floats)
constexpr int OFF_ENC    = 0;
constexpr int OFF_ASSIGN = NPTS * 32;                 // 262144
constexpr int OFF_KNN    = OFF_ASSIGN + NPTS * KC;    // 327680
constexpr int OFF_STATS  = OFF_KNN + NPTS * NNB;      // 368640
constexpr int OFF_LOSS   = OFF_STATS + NPTS * 3;      // 393216 (loss, intra, inter)

// Workspace layout (float offsets)
constexpr int WS_CNORM = 0;            // 8
constexpr int WS_INTER = 8;            // 1
constexpr int WS_XX    = 16;           // 8192 row norms
constexpr int WS_INTRA = 16 + NPTS;    // 512 block partials
constexpr int WS_CAND  = 16 + NPTS + 512; // float2[NPTS][40] candidates (key, idx)
constexpr size_t XB_OFF = 4u << 20;    // byte offset of packed bf16 copy of x (8 MB)

typedef short bf16x8 __attribute__((ext_vector_type(8)));
typedef float f32x16 __attribute__((ext_vector_type(16)));

__device__ __forceinline__ float waveAllSum(float v) {
#pragma unroll
  for (int m = 1; m < 64; m <<= 1) v += __shfl_xor(v, m);
  return v;
}
__device__ __forceinline__ float waveAllMax(float v) {
#pragma unroll
  for (int m = 1; m < 64; m <<= 1) v = fmaxf(v, __shfl_xor(v, m));
  return v;
}

__device__ __forceinline__ unsigned short f2bf(float f) {
  unsigned u = __float_as_uint(f);
  unsigned r = (u + 0x7FFFu + ((u >> 16) & 1u)) >> 16;  // RNE
  return (unsigned short)r;
}

// async global(16B/lane) -> LDS, linear dest (wave-uniform base + lane*16)
__device__ __forceinline__ void gload16(const void* g, void* lds) {
  __builtin_amdgcn_global_load_lds(
      (const __attribute__((address_space(1))) unsigned int*)(unsigned long long)g,
      (__attribute__((address_space(3))) unsigned int*)(unsigned)(unsigned long long)lds,
      16, 0, 0);
}

// ---------------- k_init: center norms + inter-cluster distance ----------------
__global__ void k_init(const float* __restrict__ cc, float* __restrict__ ws) {
  int t = threadIdx.x;
  if (t < KC) {
    float s = 0.f;
    for (int j = 0; j < DIM; j++) { float v = cc[t * DIM + j]; s = fmaf(v, v, s); }
    ws[WS_CNORM + t] = s;
  }
  __syncthreads();
  int i = t >> 3, j = t & 7;
  float dot = 0.f;
  for (int u = 0; u < DIM; u++) dot = fmaf(cc[i * DIM + u], cc[j * DIM + u], dot);
  float d2 = ws[WS_CNORM + i] + ws[WS_CNORM + j] - 2.f * dot;
  float d = d2 > 0.f ? sqrtf(d2) : 0.f;
  float v = (i != j) ? d : 0.f;
  v = waveAllSum(v);
  if (t == 0) ws[WS_INTER] = v / 56.f;
}

// ---------------- k_stats: row stats + soft assignment + intra partials --------
__global__ __launch_bounds__(256) void k_stats(
    const float* __restrict__ x, const float* __restrict__ cc,
    const float* __restrict__ temp, const float* __restrict__ cw,
    float* __restrict__ out, float* __restrict__ ws) {
  __shared__ __align__(16) float Cs[KC * DIM];
  __shared__ float cns[KC], cwS[KC];
  __shared__ float intraS[4];
  int tid = threadIdx.x;
  for (int i = tid * 4; i < KC * DIM; i += 1024)
    *(float4*)&Cs[i] = *(const float4*)&cc[i];
  if (tid < KC) { cns[tid] = ws[WS_CNORM + tid]; cwS[tid] = cw[tid]; }
  __syncthreads();
  float T = temp[0];
  int w = tid >> 6, l = tid & 63;
  float intra_acc = 0.f;
  for (int q = 0; q < 4; q++) {
    int row = blockIdx.x * 16 + w * 4 + q;
    float4 v0 = *(const float4*)&x[row * DIM + l * 4];
    float4 v1 = *(const float4*)&x[row * DIM + 256 + l * 4];
    float xv[8] = {v0.x, v0.y, v0.z, v0.w, v1.x, v1.y, v1.z, v1.w};
    float s1 = 0.f, s2 = 0.f, mx = -3e38f;
#pragma unroll
    for (int u = 0; u < 8; u++) { s1 += xv[u]; s2 = fmaf(xv[u], xv[u], s2); mx = fmaxf(mx, xv[u]); }
    s1 = waveAllSum(s1); s2 = waveAllSum(s2); mx = waveAllMax(mx);
    float e = 0.f, ex = 0.f;
#pragma unroll
    for (int u = 0; u < 8; u++) { float p = expf(xv[u] - mx); e += p; ex = fmaf(xv[u], p, ex); }
    e = waveAllSum(e); ex = waveAllSum(ex);
    float dk[KC];
#pragma unroll
    for (int k = 0; k < KC; k++) {
      float4 c0 = *(const float4*)&Cs[k * DIM + l * 4];
      float4 c1 = *(const float4*)&Cs[k * DIM + 256 + l * 4];
      float d = v0.x * c0.x + v0.y * c0.y + v0.z * c0.z + v0.w * c0.w
              + v1.x * c1.x + v1.y * c1.y + v1.z * c1.z + v1.w * c1.w;
      dk[k] = waveAllSum(d);
    }
    float mu = s1 / 512.f;
    float var = (s2 - 512.f * mu * mu) / 511.f;
    if (var < 0.f) var = 0.f;
    float sd = sqrtf(var) + 1e-8f;
    float lse = mx + logf(e);
    float ent = lse - ex / e;
    float dcv[KC], am = -3e38f;
#pragma unroll
    for (int k = 0; k < KC; k++) {
      float d2 = s2 + cns[k] - 2.f * dk[k];
      dcv[k] = d2 > 0.f ? sqrtf(d2) : 0.f;
      am = fmaxf(am, -dcv[k] / T);
    }
    float psum = 0.f, pv[KC];
#pragma unroll
    for (int k = 0; k < KC; k++) { pv[k] = expf(-dcv[k] / T - am); psum += pv[k]; }
    float il = 0.f, asg[KC];
#pragma unroll
    for (int k = 0; k < KC; k++) { asg[k] = pv[k] / psum * cwS[k]; il = fmaf(dcv[k], asg[k], il); }
    intra_acc += il;
    if (l == 0) {
      ws[WS_XX + row] = s2;
      out[OFF_STATS + row * 3 + 0] = mu;
      out[OFF_STATS + row * 3 + 1] = sd;
      out[OFF_STATS + row * 3 + 2] = ent;
#pragma unroll
      for (int k = 0; k < KC; k++) out[OFF_ASSIGN + row * KC + k] = asg[k];
    }
  }
  if (l == 0) intraS[w] = intra_acc;
  __syncthreads();
  if (tid == 0)
    ws[WS_INTRA + blockIdx.x] = intraS[0] + intraS[1] + intraS[2] + intraS[3];
}

// ---------------- k_final: scalar loss outputs ----------------
__global__ void k_final(float* __restrict__ out, const float* __restrict__ ws) {
  __shared__ float ps[4];
  int t = threadIdx.x;
  float v = ws[WS_INTRA + t] + ws[WS_INTRA + t + 256];
  v = waveAllSum(v);
  if ((t & 63) == 0) ps[t >> 6] = v;
  __syncthreads();
  if (t == 0) {
    float intra = (ps[0] + ps[1] + ps[2] + ps[3]) / (8192.f * 8.f);
    float inter = ws[WS_INTER];
    out[OFF_LOSS + 0] = intra - 0.1f * inter;
    out[OFF_LOSS + 1] = intra;
    out[OFF_LOSS + 2] = inter;
  }
}

// ---------------- k_pack: x f32 -> bf16 packed into MFMA fragment layout ------
__global__ __launch_bounds__(256) void k_pack(const float* __restrict__ x,
                                              unsigned short* __restrict__ xp) {
  int t = blockIdx.x * 256 + threadIdx.x;   // one thread per 16B unit-lane
  int lane = t & 63;
  int kk = (t >> 6) & 31;
  int grp = t >> 11;
  int point = grp * 32 + (lane & 31);
  int k0 = kk * 16 + (lane >> 5) * 8;
  const float* src = x + point * DIM + k0;
  float4 v0 = *(const float4*)src;
  float4 v1 = *(const float4*)(src + 4);
  bf16x8 o;
  o[0] = (short)f2bf(v0.x); o[1] = (short)f2bf(v0.y);
  o[2] = (short)f2bf(v0.z); o[3] = (short)f2bf(v0.w);
  o[4] = (short)f2bf(v1.x); o[5] = (short)f2bf(v1.y);
  o[6] = (short)f2bf(v1.z); o[7] = (short)f2bf(v1.w);
  *(bf16x8*)(xp + (size_t)t * 8) = o;
}

// ---------------- k_gemm4: 128-row blocks, paired col groups, clean-d2 top-5 --
// grid 256 = 64 row-blocks x 4 col chunks, 1 block/CU (128KB LDS), 8 waves.
// Rows: 128 x 512 bf16 = 128KB staged once via gload16 (packed layout, linear).
// Cols: stream global->VGPR in PAIRS of 32-col groups: per kk = 2 gload + 4
// ds_read_b128 + 8 MFMA (MFMA-bound per CU). Swapped operands: row in lane,
// 16 cols in regs. Lane l owns rows (l&31)+{0,32,64,96} -> 4 top-5 lists.
// Selection key: clean partial p = xc - 2*dot; noise applied to finalists in
// k_merge (1e-6-scale -> output diff < 1e-5).

__global__ __launch_bounds__(512, 2) void k_gemm4(
    const unsigned short* __restrict__ xp, float* __restrict__ ws) {
  __shared__ __align__(16) char SMEM[131072];
  const int tid = threadIdx.x;
  const int l = tid & 63, w = tid >> 6;
  const int lh = l >> 5, l31 = l & 31;

  // XCD-chunked swizzle: XCD k (flat%8) owns works k*32..k*32+31 (same cchunk)
  const int flat = blockIdx.x;
  const int work = (flat & 7) * 32 + (flat >> 3);
  const int rb = work & 63;           // row-block (128 rows)
  const int cchunk = work >> 6;       // col chunk (2048 cols)
  const int rowbase = rb * 128;
  const int colbase = cchunk * 2048;

  const float* xxg = ws + WS_XX;
  float2* candp = (float2*)(ws + WS_CAND);

  // ---- stage 128 rows x 512 k once: 128 x 1KB units, wave w stages 16 units
  {
    const int rg0 = rb * 4;
#pragma unroll
    for (int i = 0; i < 16; i++) {
      const int u = w * 16 + i;                             // u = g*32 + kk
      const size_t src = ((size_t)(rg0 + (u >> 5)) * 32 + (u & 31)) * 512 + l * 8;
      gload16(xp + src, SMEM + u * 1024);
    }
  }

  int myrow[4];
#pragma unroll
  for (int rf = 0; rf < 4; rf++) myrow[rf] = rowbase + l31 + 32 * rf;

  float k5[4][5]; int i5[4][5];
#pragma unroll
  for (int rf = 0; rf < 4; rf++)
#pragma unroll
    for (int s = 0; s < 5; s++) { k5[rf][s] = 3e38f; i5[rf][s] = -1; }

  __syncthreads();  // rows resident; only barrier before merge phase

  for (int iter = 0; iter < 4; iter++) {
    const int g0 = iter * 16 + w * 2;           // this wave's col-group pair
    const unsigned short* colp0 = xp + ((size_t)(cchunk * 64 + g0) << 14) + l * 8;
    const unsigned short* colp1 = colp0 + 16384;

    f32x16 acc[2][4];
#pragma unroll
    for (int cg = 0; cg < 2; cg++)
#pragma unroll
      for (int rf = 0; rf < 4; rf++)
#pragma unroll
        for (int r = 0; r < 16; r++) acc[cg][rf][r] = 0.f;

#pragma unroll 8
    for (int kk = 0; kk < 32; kk++) {
      bf16x8 c0 = *(const bf16x8*)(colp0 + kk * 512);
      bf16x8 c1 = *(const bf16x8*)(colp1 + kk * 512);
      const char* rp = SMEM + kk * 1024 + (l << 4);
      bf16x8 r0 = *(const bf16x8*)(rp);
      bf16x8 r1 = *(const bf16x8*)(rp + 32768);
      bf16x8 r2 = *(const bf16x8*)(rp + 65536);
      bf16x8 r3 = *(const bf16x8*)(rp + 98304);
      acc[0][0] = __builtin_amdgcn_mfma_f32_32x32x16_bf16(c0, r0, acc[0][0], 0, 0, 0);
      acc[0][1] = __builtin_amdgcn_mfma_f32_32x32x16_bf16(c0, r1, acc[0][1], 0, 0, 0);
      acc[0][2] = __builtin_amdgcn_mfma_f32_32x32x16_bf16(c0, r2, acc[0][2], 0, 0, 0);
      acc[0][3] = __builtin_amdgcn_mfma_f32_32x32x16_bf16(c0, r3, acc[0][3], 0, 0, 0);
      acc[1][0] = __builtin_amdgcn_mfma_f32_32x32x16_bf16(c1, r0, acc[1][0], 0, 0, 0);
      acc[1][1] = __builtin_amdgcn_mfma_f32_32x32x16_bf16(c1, r1, acc[1][1], 0, 0, 0);
      acc[1][2] = __builtin_amdgcn_mfma_f32_32x32x16_bf16(c1, r2, acc[1][2], 0, 0, 0);
      acc[1][3] = __builtin_amdgcn_mfma_f32_32x32x16_bf16(c1, r3, acc[1][3], 0, 0, 0);
    }

    // epilogue: pure-register clean-d2 top-5 over 8 rows' worth of 32 cols
#pragma unroll
    for (int cg = 0; cg < 2; cg++) {
      const int colt = colbase + (g0 + cg) * 32;
      float xq[16];
#pragma unroll
      for (int g = 0; g < 4; g++) {
        float4 t0 = *(const float4*)&xxg[colt + 8 * g + 4 * lh];
        xq[4*g+0]=t0.x; xq[4*g+1]=t0.y; xq[4*g+2]=t0.z; xq[4*g+3]=t0.w;
      }
#pragma unroll
      for (int rf = 0; rf < 4; rf++) {
#pragma unroll
        for (int r = 0; r < 16; r++) {
          const int c = colt + ((r & 3) + 8 * (r >> 2) + 4 * lh);
          const float p = xq[r] - 2.0f * acc[cg][rf][r];
          if (p < k5[rf][4] && c != myrow[rf]) {
            float a_ = p; int b_ = c;
#pragma unroll
            for (int s = 0; s < 5; s++) {
              if (a_ < k5[rf][s]) {
                float t_ = k5[rf][s]; k5[rf][s] = a_; a_ = t_;
                int u_ = i5[rf][s]; i5[rf][s] = b_; b_ = u_;
              }
            }
          }
        }
      }
    }
  }

  // ---- lane^32 merge (lanes l, l^32 hold the same 4 rows, other cols) ----
  float M[4][5]; int J[4][5];
#pragma unroll
  for (int rf = 0; rf < 4; rf++) {
    float m[5]; int n[5];
#pragma unroll
    for (int s = 0; s < 5; s++) { m[s] = k5[rf][s]; n[s] = i5[rf][s]; }
#pragma unroll
    for (int s = 0; s < 5; s++) {
      float ok = __shfl_xor(m[0], 32); int oi = __shfl_xor(n[0], 32);
      bool take = (m[0] < ok) || (m[0] == ok && (unsigned)n[0] <= (unsigned)oi);
      M[rf][s] = take ? m[0] : ok; J[rf][s] = take ? n[0] : oi;
      if (take) { m[0]=m[1];n[0]=n[1]; m[1]=m[2];n[1]=n[2]; m[2]=m[3];n[2]=n[3]; m[3]=m[4];n[3]=n[4]; m[4]=3e38f;n[4]=-1; }
    }
  }

  // ---- cross-wave merge via LDS: [128 rows][8 waves][5] ----
  __syncthreads();  // done reading row tile
  float2* mrg = (float2*)SMEM;
  if (l < 32) {
#pragma unroll
    for (int rf = 0; rf < 4; rf++)
#pragma unroll
      for (int s = 0; s < 5; s++)
        mrg[((l31 + 32 * rf) * 8 + w) * 5 + s] =
            make_float2(M[rf][s], __int_as_float(J[rf][s]));
  }
  __syncthreads();
  if (tid < 128) {
    const int row = tid;
    const float xr = xxg[rowbase + row];
    float2 h[8]; int p[8];
#pragma unroll
    for (int j = 0; j < 8; j++) { h[j] = mrg[(row * 8 + j) * 5]; p[j] = 0; }
    const size_t base = (size_t)(rowbase + row) * 40 + cchunk * 5;
#pragma unroll
    for (int s = 0; s < 5; s++) {
      int bj = 0; float bk = h[0].x; int bi = __float_as_int(h[0].y);
#pragma unroll
      for (int j = 1; j < 8; j++) {
        float kj = h[j].x; int ij = __float_as_int(h[j].y);
        if (kj < bk || (kj == bk && (unsigned)ij < (unsigned)bi)) { bk = kj; bi = ij; bj = j; }
      }
      candp[base + s] = make_float2(fmaxf(bk + xr, 0.f), __int_as_float(bi));
      p[bj]++;
      h[bj] = (p[bj] < 5) ? mrg[(row * 8 + bj) * 5 + p[bj]]
                          : make_float2(3e38f, __int_as_float(-1));
    }
  }
}

// ---------------- k_gemm (fallback, fp32 VALU): unchanged ----------------
__global__ __launch_bounds__(256, 2) void k_gemm(
    const float* __restrict__ x, const float* __restrict__ noise,
    float* __restrict__ ws) {
  __shared__ __align__(16) float As[16][132];
  __shared__ __align__(16) float Bs[16][132];
  __shared__ float xxc[1024];
  const int tid = threadIdx.x;
  const int tx = tid & 7, ty = tid >> 3;
  const int rowbase = blockIdx.x * 128;
  const int colbase = blockIdx.y * 1024;
  const float* xxg = ws + WS_XX;

  for (int i = tid; i < 1024; i += 256) xxc[i] = xxg[colbase + i];
  float xxr[4];
#pragma unroll
  for (int r = 0; r < 4; r++) xxr[r] = xxg[rowbase + ty * 4 + r];

  float k5[4][5]; int i5[4][5];
#pragma unroll
  for (int r = 0; r < 4; r++)
#pragma unroll
    for (int s = 0; s < 5; s++) { k5[r][s] = 3e38f; i5[r][s] = -1; }

  const int rlo = tid >> 2, kq = tid & 3;

  for (int ct = 0; ct < 8; ct++) {
    const int colt = colbase + ct * 128;
    float acc[4][16];
#pragma unroll
    for (int r = 0; r < 4; r++)
#pragma unroll
      for (int c = 0; c < 16; c++) acc[r][c] = 0.f;

    for (int kk = 0; kk < 512; kk += 16) {
      __syncthreads();
      float4 a0 = *(const float4*)&x[(rowbase + rlo) * DIM + kk + kq * 4];
      float4 a1 = *(const float4*)&x[(rowbase + rlo + 64) * DIM + kk + kq * 4];
      float4 b0 = *(const float4*)&x[(colt + rlo) * DIM + kk + kq * 4];
      float4 b1 = *(const float4*)&x[(colt + rlo + 64) * DIM + kk + kq * 4];
      As[kq * 4 + 0][rlo] = a0.x; As[kq * 4 + 1][rlo] = a0.y;
      As[kq * 4 + 2][rlo] = a0.z; As[kq * 4 + 3][rlo] = a0.w;
      As[kq * 4 + 0][rlo + 64] = a1.x; As[kq * 4 + 1][rlo + 64] = a1.y;
      As[kq * 4 + 2][rlo + 64] = a1.z; As[kq * 4 + 3][rlo + 64] = a1.w;
      Bs[kq * 4 + 0][rlo] = b0.x; Bs[kq * 4 + 1][rlo] = b0.y;
      Bs[kq * 4 + 2][rlo] = b0.z; Bs[kq * 4 + 3][rlo] = b0.w;
      Bs[kq * 4 + 0][rlo + 64] = b1.x; Bs[kq * 4 + 1][rlo + 64] = b1.y;
      Bs[kq * 4 + 2][rlo + 64] = b1.z; Bs[kq * 4 + 3][rlo + 64] = b1.w;
      __syncthreads();
#pragma unroll
      for (int k = 0; k < 16; k++) {
        float4 av = *(const float4*)&As[k][ty * 4];
        float a_[4] = {av.x, av.y, av.z, av.w};
#pragma unroll
        for (int j = 0; j < 4; j++) {
          float4 bv = *(const float4*)&Bs[k][tx * 4 + j * 32];
          float b_[4] = {bv.x, bv.y, bv.z, bv.w};
#pragma unroll
          for (int rr = 0; rr < 4; rr++)
#pragma unroll
            for (int uu = 0; uu < 4; uu++)
              acc[rr][j * 4 + uu] = fmaf(a_[rr], b_[uu], acc[rr][j * 4 + uu]);
        }
      }
    }
#pragma unroll
    for (int r = 0; r < 4; r++) {
      const int row = rowbase + ty * 4 + r;
#pragma unroll
      for (int j = 0; j < 4; j++) {
        const int cl = tx * 4 + j * 32;
        const int col = colt + cl;
        const float4 nz = *(const float4*)&noise[(size_t)row * NPTS + col];
        float nzv[4] = {nz.x, nz.y, nz.z, nz.w};
#pragma unroll
        for (int u = 0; u < 4; u++) {
          float d2 = xxr[r] + xxc[ct * 128 + cl + u] - 2.f * acc[r][j * 4 + u];
          float d = d2 > 0.f ? sqrtf(d2) : 0.f;
          float key = d + 1e-6f * nzv[u];
          int c = col + u;
          if (c != row && key < k5[r][4]) {
            float a = key; int b = c;
#pragma unroll
            for (int s = 0; s < 5; s++) {
              if (a < k5[r][s]) {
                float tf = k5[r][s]; k5[r][s] = a; a = tf;
                int ti = i5[r][s]; i5[r][s] = b; b = ti;
              }
            }
          }
        }
      }
    }
  }

#pragma unroll
  for (int r = 0; r < 4; r++) {
    const int row = rowbase + ty * 4 + r;
    float lk[5]; int li[5];
#pragma unroll
    for (int s = 0; s < 5; s++) { lk[s] = k5[r][s]; li[s] = i5[r][s]; }
#pragma unroll
    for (int s = 0; s < 5; s++) {
      float wk = lk[0]; int wi = li[0];
#pragma unroll
      for (int m = 1; m < 8; m <<= 1) {
        float k2 = __shfl_xor(wk, m); int i2 = __shfl_xor(wi, m);
        if (k2 < wk || (k2 == wk && (unsigned)i2 < (unsigned)wi)) { wk = k2; wi = i2; }
      }
      if (li[0] == wi && lk[0] == wk) {
        lk[0] = lk[1]; li[0] = li[1];
        lk[1] = lk[2]; li[1] = li[2];
        lk[2] = lk[3]; li[2] = li[3];
        lk[3] = lk[4]; li[3] = li[4];
        lk[4] = 3e38f; li[4] = -1;
      }
      if (tx == 0) {
        float2* cand = (float2*)(ws + WS_CAND);
        cand[(size_t)row * 40 + blockIdx.y * 5 + s] = make_float2(wk, __int_as_float(wi));
      }
    }
  }
}

// ---------------- k_merge: final top-5 + feats + MLP ----------------
// mode 0: cand.x is noisy key (fallback). mode 1: cand.x is clean d2; build
// noisy key = sqrt(d2) + 1e-6*noise here (20 scalar loads/row).
__global__ __launch_bounds__(256) void k_merge(
    const float* __restrict__ noise, const float* __restrict__ w1,
    const float* __restrict__ b1, const float* __restrict__ w2,
    const float* __restrict__ b2, float* __restrict__ out,
    const float* __restrict__ ws, int nslots, int mode) {
  __shared__ float w1s[16 * 64];
  __shared__ float b1s[64];
  __shared__ float w2s[64 * 32];
  __shared__ float b2s[32];
  __shared__ float featsS[4][16];
  __shared__ float hS[4][64];
  int tid = threadIdx.x;
  for (int i = tid; i < 1024; i += 256) w1s[i] = w1[i];
  for (int i = tid; i < 2048; i += 256) w2s[i] = w2[i];
  if (tid < 64) b1s[tid] = b1[tid];
  if (tid < 32) b2s[tid] = b2[tid];
  __syncthreads();
  int w = tid >> 6, l = tid & 63;
  const float2* cand = (const float2*)(ws + WS_CAND);
  for (int q = 0; q < 8; q++) {
    int row = blockIdx.x * 32 + w * 8 + q;
    float mk = 3e38f; int mi = -1;
    if (l < nslots) {
      float2 c = cand[(size_t)row * 40 + l];
      mi = __float_as_int(c.y);
      if (mode) {
        float d = sqrtf(c.x);
        mk = fmaf(1e-6f, noise[(size_t)row * NPTS + mi], d);
      } else {
        mk = c.x;
      }
    }
#pragma unroll
    for (int s = 0; s < 5; s++) {
      float wk = mk; int wi = mi;
#pragma unroll
      for (int m = 1; m < 64; m <<= 1) {
        float k2 = __shfl_xor(wk, m); int i2 = __shfl_xor(wi, m);
        if (k2 < wk || (k2 == wk && (unsigned)i2 < (unsigned)wi)) { wk = k2; wi = i2; }
      }
      if (mi == wi && mk == wk) mk = 3e38f;  // remove winner from my slot
      if (l == s) {
        float nv = noise[(size_t)row * NPTS + wi];
        float dclean = wk - 1e-6f * nv;
        out[OFF_KNN + row * NNB + s] = dclean;
        featsS[w][8 + s] = dclean;
      }
    }
    if (l < 8) featsS[w][l] = out[OFF_ASSIGN + row * KC + l];
    if (l >= 13 && l < 16) featsS[w][l] = out[OFF_STATS + row * 3 + (l - 13)];
    __syncthreads();
    float h = b1s[l];
#pragma unroll
    for (int i = 0; i < 16; i++) h = fmaf(featsS[w][i], w1s[i * 64 + l], h);
    hS[w][l] = fmaxf(h, 0.f);
    __syncthreads();
    if (l < 32) {
      float e = b2s[l];
#pragma unroll
      for (int i = 0; i < 64; i++) e = fmaf(hS[w][i], w2s[i * 32 + l], e);
      out[OFF_ENC + row * 32 + l] = e;
    }
    __syncthreads();
  }
}

extern "C" void kernel_launch(void* const* d_in, const int* in_sizes, int n_in,
                              void* d_out, int out_size, void* d_ws, size_t ws_size,
                              hipStream_t stream) {
  const float* x     = (const float*)d_in[0];
  const float* noise = (const float*)d_in[1];
  const float* cc    = (const float*)d_in[2];
  const float* w1    = (const float*)d_in[3];
  const float* b1    = (const float*)d_in[4];
  const float* w2    = (const float*)d_in[5];
  const float* b2    = (const float*)d_in[6];
  const float* temp  = (const float*)d_in[7];
  const float* cw    = (const float*)d_in[8];
  float* out = (float*)d_out;
  float* ws  = (float*)d_ws;

  const size_t need = XB_OFF + (size_t)NPTS * DIM * 2;  // 12.4 MB
  const bool fast = ws_size >= need;

  hipLaunchKernelGGL(k_init,  dim3(1),   dim3(64),  0, stream, cc, ws);
  hipLaunchKernelGGL(k_stats, dim3(512), dim3(256), 0, stream, x, cc, temp, cw, out, ws);
  hipLaunchKernelGGL(k_final, dim3(1),   dim3(256), 0, stream, out, ws);
  if (fast) {
    unsigned short* xp = (unsigned short*)((char*)d_ws + XB_OFF);
    hipLaunchKernelGGL(k_pack,  dim3(2048), dim3(256), 0, stream, x, xp);
    hipLaunchKernelGGL(k_gemm4, dim3(256),  dim3(512), 0, stream, xp, ws);
    hipLaunchKernelGGL(k_merge, dim3(256),  dim3(256), 0, stream, noise, w1, b1, w2, b2, out, ws, 20, 1);
  } else {
    hipLaunchKernelGGL(k_gemm,  dim3(64, 8), dim3(256), 0, stream, x, noise, ws);
    hipLaunchKernelGGL(k_merge, dim3(256),  dim3(256), 0, stream, noise, w1, b1, w2, b2, out, ws, 40, 0);
  }
}

// Round 7
// 200.911 us; speedup vs baseline: 2.4237x; 1.0483x over previous
//
#include <hip/hip_runtime.h>
#include <math.h>

// Problem sizes
constexpr int NPTS = 8192;
constexpr int DIM  = 512;
constexpr int KC   = 8;    // clusters
constexpr int NNB  = 5;    // neighbors

// Output layout (floats)
constexpr int OFF_ENC    = 0;
constexpr int OFF_ASSIGN = NPTS * 32;                 // 262144
constexpr int OFF_KNN    = OFF_ASSIGN + NPTS * KC;    // 327680
constexpr int OFF_STATS  = OFF_KNN + NPTS * NNB;      // 368640
constexpr int OFF_LOSS   = OFF_STATS + NPTS * 3;      // 393216 (loss, intra, inter)

// Workspace layout (float offsets)
constexpr int WS_CNORM = 0;            // 8
constexpr int WS_INTER = 8;            // 1
constexpr int WS_XX    = 16;           // 8192 row norms
constexpr int WS_INTRA = 16 + NPTS;    // 512 block partials
constexpr int WS_CAND  = 16 + NPTS + 512; // float2[NPTS][40] candidates (key, idx)
constexpr size_t XB_OFF = 4u << 20;    // byte offset of packed bf16 copy of x (8 MB)

typedef short bf16x8 __attribute__((ext_vector_type(8)));
typedef float f32x16 __attribute__((ext_vector_type(16)));

__device__ __forceinline__ float waveAllSum(float v) {
#pragma unroll
  for (int m = 1; m < 64; m <<= 1) v += __shfl_xor(v, m);
  return v;
}
__device__ __forceinline__ float waveAllMax(float v) {
#pragma unroll
  for (int m = 1; m < 64; m <<= 1) v = fmaxf(v, __shfl_xor(v, m));
  return v;
}

__device__ __forceinline__ unsigned short f2bf(float f) {
  unsigned u = __float_as_uint(f);
  unsigned r = (u + 0x7FFFu + ((u >> 16) & 1u)) >> 16;  // RNE
  return (unsigned short)r;
}

// async global(16B/lane) -> LDS, linear dest (wave-uniform base + lane*16)
__device__ __forceinline__ void gload16(const void* g, void* lds) {
  __builtin_amdgcn_global_load_lds(
      (const __attribute__((address_space(1))) unsigned int*)(unsigned long long)g,
      (__attribute__((address_space(3))) unsigned int*)(unsigned)(unsigned long long)lds,
      16, 0, 0);
}

// ---------------- k_init: center norms + inter-cluster distance ----------------
__global__ void k_init(const float* __restrict__ cc, float* __restrict__ ws) {
  int t = threadIdx.x;
  if (t < KC) {
    float s = 0.f;
    for (int j = 0; j < DIM; j++) { float v = cc[t * DIM + j]; s = fmaf(v, v, s); }
    ws[WS_CNORM + t] = s;
  }
  __syncthreads();
  int i = t >> 3, j = t & 7;
  float dot = 0.f;
  for (int u = 0; u < DIM; u++) dot = fmaf(cc[i * DIM + u], cc[j * DIM + u], dot);
  float d2 = ws[WS_CNORM + i] + ws[WS_CNORM + j] - 2.f * dot;
  float d = d2 > 0.f ? sqrtf(d2) : 0.f;
  float v = (i != j) ? d : 0.f;
  v = waveAllSum(v);
  if (t == 0) ws[WS_INTER] = v / 56.f;
}

// ---------------- k_stats: row stats + soft assignment + intra partials --------
__global__ __launch_bounds__(256) void k_stats(
    const float* __restrict__ x, const float* __restrict__ cc,
    const float* __restrict__ temp, const float* __restrict__ cw,
    float* __restrict__ out, float* __restrict__ ws) {
  __shared__ __align__(16) float Cs[KC * DIM];
  __shared__ float cns[KC], cwS[KC];
  __shared__ float intraS[4];
  int tid = threadIdx.x;
  for (int i = tid * 4; i < KC * DIM; i += 1024)
    *(float4*)&Cs[i] = *(const float4*)&cc[i];
  if (tid < KC) { cns[tid] = ws[WS_CNORM + tid]; cwS[tid] = cw[tid]; }
  __syncthreads();
  float T = temp[0];
  int w = tid >> 6, l = tid & 63;
  float intra_acc = 0.f;
  for (int q = 0; q < 4; q++) {
    int row = blockIdx.x * 16 + w * 4 + q;
    float4 v0 = *(const float4*)&x[row * DIM + l * 4];
    float4 v1 = *(const float4*)&x[row * DIM + 256 + l * 4];
    float xv[8] = {v0.x, v0.y, v0.z, v0.w, v1.x, v1.y, v1.z, v1.w};
    float s1 = 0.f, s2 = 0.f, mx = -3e38f;
#pragma unroll
    for (int u = 0; u < 8; u++) { s1 += xv[u]; s2 = fmaf(xv[u], xv[u], s2); mx = fmaxf(mx, xv[u]); }
    s1 = waveAllSum(s1); s2 = waveAllSum(s2); mx = waveAllMax(mx);
    float e = 0.f, ex = 0.f;
#pragma unroll
    for (int u = 0; u < 8; u++) { float p = expf(xv[u] - mx); e += p; ex = fmaf(xv[u], p, ex); }
    e = waveAllSum(e); ex = waveAllSum(ex);
    float dk[KC];
#pragma unroll
    for (int k = 0; k < KC; k++) {
      float4 c0 = *(const float4*)&Cs[k * DIM + l * 4];
      float4 c1 = *(const float4*)&Cs[k * DIM + 256 + l * 4];
      float d = v0.x * c0.x + v0.y * c0.y + v0.z * c0.z + v0.w * c0.w
              + v1.x * c1.x + v1.y * c1.y + v1.z * c1.z + v1.w * c1.w;
      dk[k] = waveAllSum(d);
    }
    float mu = s1 / 512.f;
    float var = (s2 - 512.f * mu * mu) / 511.f;
    if (var < 0.f) var = 0.f;
    float sd = sqrtf(var) + 1e-8f;
    float lse = mx + logf(e);
    float ent = lse - ex / e;
    float dcv[KC], am = -3e38f;
#pragma unroll
    for (int k = 0; k < KC; k++) {
      float d2 = s2 + cns[k] - 2.f * dk[k];
      dcv[k] = d2 > 0.f ? sqrtf(d2) : 0.f;
      am = fmaxf(am, -dcv[k] / T);
    }
    float psum = 0.f, pv[KC];
#pragma unroll
    for (int k = 0; k < KC; k++) { pv[k] = expf(-dcv[k] / T - am); psum += pv[k]; }
    float il = 0.f, asg[KC];
#pragma unroll
    for (int k = 0; k < KC; k++) { asg[k] = pv[k] / psum * cwS[k]; il = fmaf(dcv[k], asg[k], il); }
    intra_acc += il;
    if (l == 0) {
      ws[WS_XX + row] = s2;
      out[OFF_STATS + row * 3 + 0] = mu;
      out[OFF_STATS + row * 3 + 1] = sd;
      out[OFF_STATS + row * 3 + 2] = ent;
#pragma unroll
      for (int k = 0; k < KC; k++) out[OFF_ASSIGN + row * KC + k] = asg[k];
    }
  }
  if (l == 0) intraS[w] = intra_acc;
  __syncthreads();
  if (tid == 0)
    ws[WS_INTRA + blockIdx.x] = intraS[0] + intraS[1] + intraS[2] + intraS[3];
}

// ---------------- k_final: scalar loss outputs ----------------
__global__ void k_final(float* __restrict__ out, const float* __restrict__ ws) {
  __shared__ float ps[4];
  int t = threadIdx.x;
  float v = ws[WS_INTRA + t] + ws[WS_INTRA + t + 256];
  v = waveAllSum(v);
  if ((t & 63) == 0) ps[t >> 6] = v;
  __syncthreads();
  if (t == 0) {
    float intra = (ps[0] + ps[1] + ps[2] + ps[3]) / (8192.f * 8.f);
    float inter = ws[WS_INTER];
    out[OFF_LOSS + 0] = intra - 0.1f * inter;
    out[OFF_LOSS + 1] = intra;
    out[OFF_LOSS + 2] = inter;
  }
}

// ---------------- k_pack: x f32 -> bf16 packed into MFMA fragment layout ------
__global__ __launch_bounds__(256) void k_pack(const float* __restrict__ x,
                                              unsigned short* __restrict__ xp) {
  int t = blockIdx.x * 256 + threadIdx.x;   // one thread per 16B unit-lane
  int lane = t & 63;
  int kk = (t >> 6) & 31;
  int grp = t >> 11;
  int point = grp * 32 + (lane & 31);
  int k0 = kk * 16 + (lane >> 5) * 8;
  const float* src = x + point * DIM + k0;
  float4 v0 = *(const float4*)src;
  float4 v1 = *(const float4*)(src + 4);
  bf16x8 o;
  o[0] = (short)f2bf(v0.x); o[1] = (short)f2bf(v0.y);
  o[2] = (short)f2bf(v0.z); o[3] = (short)f2bf(v0.w);
  o[4] = (short)f2bf(v1.x); o[5] = (short)f2bf(v1.y);
  o[6] = (short)f2bf(v1.z); o[7] = (short)f2bf(v1.w);
  *(bf16x8*)(xp + (size_t)t * 8) = o;
}

// ---------------- k_gemm5: software-pipelined MFMA + clean-d2 top-5 -----------
// grid 256 = 64 row-blocks x 4 col chunks, 1 block/CU (128KB LDS), 8 waves.
// Rows: 128 x 512 bf16 = 128KB staged once via gload16. Cols: stream
// global->VGPR with EXPLICIT 4-deep prefetch ring; row frags 2-deep from LDS.
// Per kk: 2 col loads + 4 ds_read_b128 + 8 MFMA, no barriers in the K loop.
// Swapped operands: row in lane, 16 cols in regs. Lane l owns rows
// (l&31)+{0,32,64,96}. Clean partial p = xc - 2*dot; noise applied to the
// 20 finalists in k_merge (1e-6-scale -> output diff < 1e-5).

__global__ __launch_bounds__(512, 2) void k_gemm5(
    const unsigned short* __restrict__ xp, float* __restrict__ ws) {
  __shared__ __align__(16) char SMEM[131072];
  const int tid = threadIdx.x;
  const int l = tid & 63, w = tid >> 6;
  const int lh = l >> 5, l31 = l & 31;

  // XCD-chunked swizzle: XCD k (flat%8) owns works k*32..k*32+31 (same cchunk)
  const int flat = blockIdx.x;
  const int work = (flat & 7) * 32 + (flat >> 3);
  const int rb = work & 63;           // row-block (128 rows)
  const int cchunk = work >> 6;       // col chunk (2048 cols)
  const int rowbase = rb * 128;
  const int colbase = cchunk * 2048;

  const float* xxg = ws + WS_XX;
  float2* candp = (float2*)(ws + WS_CAND);

  // ---- stage 128 rows x 512 k once: 128 x 1KB units, wave w stages 16 units
  {
    const int rg0 = rb * 4;
#pragma unroll
    for (int i = 0; i < 16; i++) {
      const int u = w * 16 + i;                             // u = g*32 + kk
      const size_t src = ((size_t)(rg0 + (u >> 5)) * 32 + (u & 31)) * 512 + l * 8;
      gload16(xp + src, SMEM + u * 1024);
    }
  }

  int myrow[4];
#pragma unroll
  for (int rf = 0; rf < 4; rf++) myrow[rf] = rowbase + l31 + 32 * rf;

  float k5[4][5]; int i5[4][5];
#pragma unroll
  for (int rf = 0; rf < 4; rf++)
#pragma unroll
    for (int s = 0; s < 5; s++) { k5[rf][s] = 3e38f; i5[rf][s] = -1; }

  __syncthreads();  // rows resident; only barrier before merge phase

  const char* rbase = SMEM + (l << 4);

  for (int iter = 0; iter < 4; iter++) {
    const int g0 = iter * 16 + w * 2;           // this wave's col-group pair
    const unsigned short* colp0 = xp + ((size_t)(cchunk * 64 + g0) << 14) + l * 8;
    const unsigned short* colp1 = colp0 + 16384;

    f32x16 acc[2][4];
#pragma unroll
    for (int cg = 0; cg < 2; cg++)
#pragma unroll
      for (int rf = 0; rf < 4; rf++)
#pragma unroll
        for (int r = 0; r < 16; r++) acc[cg][rf][r] = 0.f;

    // ---- software pipeline: 4-deep col prefetch, 2-deep row prefetch ----
    bf16x8 pc0[4], pc1[4];     // col frag ring [kk+0..kk+3]
    bf16x8 pr[2][4];           // row frag ring [kk+0..kk+1][rf]
#pragma unroll
    for (int s = 0; s < 4; s++) {
      pc0[s] = *(const bf16x8*)(colp0 + s * 512);
      pc1[s] = *(const bf16x8*)(colp1 + s * 512);
    }
#pragma unroll
    for (int s = 0; s < 2; s++) {
      const char* rp = rbase + s * 1024;
      pr[s][0] = *(const bf16x8*)(rp);
      pr[s][1] = *(const bf16x8*)(rp + 32768);
      pr[s][2] = *(const bf16x8*)(rp + 65536);
      pr[s][3] = *(const bf16x8*)(rp + 98304);
    }

#pragma unroll
    for (int kk = 0; kk < 32; kk++) {
      const bf16x8 c0 = pc0[kk & 3], c1 = pc1[kk & 3];
      const bf16x8 r0 = pr[kk & 1][0], r1 = pr[kk & 1][1];
      const bf16x8 r2 = pr[kk & 1][2], r3 = pr[kk & 1][3];
      __builtin_amdgcn_s_setprio(1);
      acc[0][0] = __builtin_amdgcn_mfma_f32_32x32x16_bf16(c0, r0, acc[0][0], 0, 0, 0);
      acc[0][1] = __builtin_amdgcn_mfma_f32_32x32x16_bf16(c0, r1, acc[0][1], 0, 0, 0);
      acc[0][2] = __builtin_amdgcn_mfma_f32_32x32x16_bf16(c0, r2, acc[0][2], 0, 0, 0);
      acc[0][3] = __builtin_amdgcn_mfma_f32_32x32x16_bf16(c0, r3, acc[0][3], 0, 0, 0);
      acc[1][0] = __builtin_amdgcn_mfma_f32_32x32x16_bf16(c1, r0, acc[1][0], 0, 0, 0);
      acc[1][1] = __builtin_amdgcn_mfma_f32_32x32x16_bf16(c1, r1, acc[1][1], 0, 0, 0);
      acc[1][2] = __builtin_amdgcn_mfma_f32_32x32x16_bf16(c1, r2, acc[1][2], 0, 0, 0);
      acc[1][3] = __builtin_amdgcn_mfma_f32_32x32x16_bf16(c1, r3, acc[1][3], 0, 0, 0);
      __builtin_amdgcn_s_setprio(0);
      if (kk < 28) {
        pc0[kk & 3] = *(const bf16x8*)(colp0 + (kk + 4) * 512);
        pc1[kk & 3] = *(const bf16x8*)(colp1 + (kk + 4) * 512);
      }
      if (kk < 30) {
        const char* rp = rbase + (kk + 2) * 1024;
        pr[kk & 1][0] = *(const bf16x8*)(rp);
        pr[kk & 1][1] = *(const bf16x8*)(rp + 32768);
        pr[kk & 1][2] = *(const bf16x8*)(rp + 65536);
        pr[kk & 1][3] = *(const bf16x8*)(rp + 98304);
      }
    }

    // epilogue: pure-register clean-d2 top-5 over 4 rows x 32 cols
#pragma unroll
    for (int cg = 0; cg < 2; cg++) {
      const int colt = colbase + (g0 + cg) * 32;
      float xq[16];
#pragma unroll
      for (int g = 0; g < 4; g++) {
        float4 t0 = *(const float4*)&xxg[colt + 8 * g + 4 * lh];
        xq[4*g+0]=t0.x; xq[4*g+1]=t0.y; xq[4*g+2]=t0.z; xq[4*g+3]=t0.w;
      }
#pragma unroll
      for (int rf = 0; rf < 4; rf++) {
#pragma unroll
        for (int r = 0; r < 16; r++) {
          const int c = colt + ((r & 3) + 8 * (r >> 2) + 4 * lh);
          const float p = xq[r] - 2.0f * acc[cg][rf][r];
          if (p < k5[rf][4] && c != myrow[rf]) {
            float a_ = p; int b_ = c;
#pragma unroll
            for (int s = 0; s < 5; s++) {
              if (a_ < k5[rf][s]) {
                float t_ = k5[rf][s]; k5[rf][s] = a_; a_ = t_;
                int u_ = i5[rf][s]; i5[rf][s] = b_; b_ = u_;
              }
            }
          }
        }
      }
    }
  }

  // ---- lane^32 merge (lanes l, l^32 hold the same 4 rows, other cols) ----
  float M[4][5]; int J[4][5];
#pragma unroll
  for (int rf = 0; rf < 4; rf++) {
    float m[5]; int n[5];
#pragma unroll
    for (int s = 0; s < 5; s++) { m[s] = k5[rf][s]; n[s] = i5[rf][s]; }
#pragma unroll
    for (int s = 0; s < 5; s++) {
      float ok = __shfl_xor(m[0], 32); int oi = __shfl_xor(n[0], 32);
      bool take = (m[0] < ok) || (m[0] == ok && (unsigned)n[0] <= (unsigned)oi);
      M[rf][s] = take ? m[0] : ok; J[rf][s] = take ? n[0] : oi;
      if (take) { m[0]=m[1];n[0]=n[1]; m[1]=m[2];n[1]=n[2]; m[2]=m[3];n[2]=n[3]; m[3]=m[4];n[3]=n[4]; m[4]=3e38f;n[4]=-1; }
    }
  }

  // ---- cross-wave merge via LDS: [128 rows][8 waves][5] ----
  __syncthreads();  // done reading row tile
  float2* mrg = (float2*)SMEM;
  if (l < 32) {
#pragma unroll
    for (int rf = 0; rf < 4; rf++)
#pragma unroll
      for (int s = 0; s < 5; s++)
        mrg[((l31 + 32 * rf) * 8 + w) * 5 + s] =
            make_float2(M[rf][s], __int_as_float(J[rf][s]));
  }
  __syncthreads();
  if (tid < 128) {
    const int row = tid;
    const float xr = xxg[rowbase + row];
    float2 h[8]; int p[8];
#pragma unroll
    for (int j = 0; j < 8; j++) { h[j] = mrg[(row * 8 + j) * 5]; p[j] = 0; }
    const size_t base = (size_t)(rowbase + row) * 40 + cchunk * 5;
#pragma unroll
    for (int s = 0; s < 5; s++) {
      int bj = 0; float bk = h[0].x; int bi = __float_as_int(h[0].y);
#pragma unroll
      for (int j = 1; j < 8; j++) {
        float kj = h[j].x; int ij = __float_as_int(h[j].y);
        if (kj < bk || (kj == bk && (unsigned)ij < (unsigned)bi)) { bk = kj; bi = ij; bj = j; }
      }
      candp[base + s] = make_float2(fmaxf(bk + xr, 0.f), __int_as_float(bi));
      p[bj]++;
      h[bj] = (p[bj] < 5) ? mrg[(row * 8 + bj) * 5 + p[bj]]
                          : make_float2(3e38f, __int_as_float(-1));
    }
  }
}

// ---------------- k_gemm (fallback, fp32 VALU): unchanged ----------------
__global__ __launch_bounds__(256, 2) void k_gemm(
    const float* __restrict__ x, const float* __restrict__ noise,
    float* __restrict__ ws) {
  __shared__ __align__(16) float As[16][132];
  __shared__ __align__(16) float Bs[16][132];
  __shared__ float xxc[1024];
  const int tid = threadIdx.x;
  const int tx = tid & 7, ty = tid >> 3;
  const int rowbase = blockIdx.x * 128;
  const int colbase = blockIdx.y * 1024;
  const float* xxg = ws + WS_XX;

  for (int i = tid; i < 1024; i += 256) xxc[i] = xxg[colbase + i];
  float xxr[4];
#pragma unroll
  for (int r = 0; r < 4; r++) xxr[r] = xxg[rowbase + ty * 4 + r];

  float k5[4][5]; int i5[4][5];
#pragma unroll
  for (int r = 0; r < 4; r++)
#pragma unroll
    for (int s = 0; s < 5; s++) { k5[r][s] = 3e38f; i5[r][s] = -1; }

  const int rlo = tid >> 2, kq = tid & 3;

  for (int ct = 0; ct < 8; ct++) {
    const int colt = colbase + ct * 128;
    float acc[4][16];
#pragma unroll
    for (int r = 0; r < 4; r++)
#pragma unroll
      for (int c = 0; c < 16; c++) acc[r][c] = 0.f;

    for (int kk = 0; kk < 512; kk += 16) {
      __syncthreads();
      float4 a0 = *(const float4*)&x[(rowbase + rlo) * DIM + kk + kq * 4];
      float4 a1 = *(const float4*)&x[(rowbase + rlo + 64) * DIM + kk + kq * 4];
      float4 b0 = *(const float4*)&x[(colt + rlo) * DIM + kk + kq * 4];
      float4 b1 = *(const float4*)&x[(colt + rlo + 64) * DIM + kk + kq * 4];
      As[kq * 4 + 0][rlo] = a0.x; As[kq * 4 + 1][rlo] = a0.y;
      As[kq * 4 + 2][rlo] = a0.z; As[kq * 4 + 3][rlo] = a0.w;
      As[kq * 4 + 0][rlo + 64] = a1.x; As[kq * 4 + 1][rlo + 64] = a1.y;
      As[kq * 4 + 2][rlo + 64] = a1.z; As[kq * 4 + 3][rlo + 64] = a1.w;
      Bs[kq * 4 + 0][rlo] = b0.x; Bs[kq * 4 + 1][rlo] = b0.y;
      Bs[kq * 4 + 2][rlo] = b0.z; Bs[kq * 4 + 3][rlo] = b0.w;
      Bs[kq * 4 + 0][rlo + 64] = b1.x; Bs[kq * 4 + 1][rlo + 64] = b1.y;
      Bs[kq * 4 + 2][rlo + 64] = b1.z; Bs[kq * 4 + 3][rlo + 64] = b1.w;
      __syncthreads();
#pragma unroll
      for (int k = 0; k < 16; k++) {
        float4 av = *(const float4*)&As[k][ty * 4];
        float a_[4] = {av.x, av.y, av.z, av.w};
#pragma unroll
        for (int j = 0; j < 4; j++) {
          float4 bv = *(const float4*)&Bs[k][tx * 4 + j * 32];
          float b_[4] = {bv.x, bv.y, bv.z, bv.w};
#pragma unroll
          for (int rr = 0; rr < 4; rr++)
#pragma unroll
            for (int uu = 0; uu < 4; uu++)
              acc[rr][j * 4 + uu] = fmaf(a_[rr], b_[uu], acc[rr][j * 4 + uu]);
        }
      }
    }
#pragma unroll
    for (int r = 0; r < 4; r++) {
      const int row = rowbase + ty * 4 + r;
#pragma unroll
      for (int j = 0; j < 4; j++) {
        const int cl = tx * 4 + j * 32;
        const int col = colt + cl;
        const float4 nz = *(const float4*)&noise[(size_t)row * NPTS + col];
        float nzv[4] = {nz.x, nz.y, nz.z, nz.w};
#pragma unroll
        for (int u = 0; u < 4; u++) {
          float d2 = xxr[r] + xxc[ct * 128 + cl + u] - 2.f * acc[r][j * 4 + u];
          float d = d2 > 0.f ? sqrtf(d2) : 0.f;
          float key = d + 1e-6f * nzv[u];
          int c = col + u;
          if (c != row && key < k5[r][4]) {
            float a = key; int b = c;
#pragma unroll
            for (int s = 0; s < 5; s++) {
              if (a < k5[r][s]) {
                float tf = k5[r][s]; k5[r][s] = a; a = tf;
                int ti = i5[r][s]; i5[r][s] = b; b = ti;
              }
            }
          }
        }
      }
    }
  }

#pragma unroll
  for (int r = 0; r < 4; r++) {
    const int row = rowbase + ty * 4 + r;
    float lk[5]; int li[5];
#pragma unroll
    for (int s = 0; s < 5; s++) { lk[s] = k5[r][s]; li[s] = i5[r][s]; }
#pragma unroll
    for (int s = 0; s < 5; s++) {
      float wk = lk[0]; int wi = li[0];
#pragma unroll
      for (int m = 1; m < 8; m <<= 1) {
        float k2 = __shfl_xor(wk, m); int i2 = __shfl_xor(wi, m);
        if (k2 < wk || (k2 == wk && (unsigned)i2 < (unsigned)wi)) { wk = k2; wi = i2; }
      }
      if (li[0] == wi && lk[0] == wk) {
        lk[0] = lk[1]; li[0] = li[1];
        lk[1] = lk[2]; li[1] = li[2];
        lk[2] = lk[3]; li[2] = li[3];
        lk[3] = lk[4]; li[3] = li[4];
        lk[4] = 3e38f; li[4] = -1;
      }
      if (tx == 0) {
        float2* cand = (float2*)(ws + WS_CAND);
        cand[(size_t)row * 40 + blockIdx.y * 5 + s] = make_float2(wk, __int_as_float(wi));
      }
    }
  }
}

// ---------------- k_merge: final top-5 + feats + MLP ----------------
// mode 0: cand.x is noisy key (fallback). mode 1: cand.x is clean d2; build
// noisy key = sqrt(d2) + 1e-6*noise here (20 scalar loads/row).
__global__ __launch_bounds__(256) void k_merge(
    const float* __restrict__ noise, const float* __restrict__ w1,
    const float* __restrict__ b1, const float* __restrict__ w2,
    const float* __restrict__ b2, float* __restrict__ out,
    const float* __restrict__ ws, int nslots, int mode) {
  __shared__ float w1s[16 * 64];
  __shared__ float b1s[64];
  __shared__ float w2s[64 * 32];
  __shared__ float b2s[32];
  __shared__ float featsS[4][16];
  __shared__ float hS[4][64];
  int tid = threadIdx.x;
  for (int i = tid; i < 1024; i += 256) w1s[i] = w1[i];
  for (int i = tid; i < 2048; i += 256) w2s[i] = w2[i];
  if (tid < 64) b1s[tid] = b1[tid];
  if (tid < 32) b2s[tid] = b2[tid];
  __syncthreads();
  int w = tid >> 6, l = tid & 63;
  const float2* cand = (const float2*)(ws + WS_CAND);
  for (int q = 0; q < 8; q++) {
    int row = blockIdx.x * 32 + w * 8 + q;
    float mk = 3e38f; int mi = -1;
    if (l < nslots) {
      float2 c = cand[(size_t)row * 40 + l];
      mi = __float_as_int(c.y);
      if (mode) {
        float d = sqrtf(c.x);
        mk = fmaf(1e-6f, noise[(size_t)row * NPTS + mi], d);
      } else {
        mk = c.x;
      }
    }
#pragma unroll
    for (int s = 0; s < 5; s++) {
      float wk = mk; int wi = mi;
#pragma unroll
      for (int m = 1; m < 64; m <<= 1) {
        float k2 = __shfl_xor(wk, m); int i2 = __shfl_xor(wi, m);
        if (k2 < wk || (k2 == wk && (unsigned)i2 < (unsigned)wi)) { wk = k2; wi = i2; }
      }
      if (mi == wi && mk == wk) mk = 3e38f;  // remove winner from my slot
      if (l == s) {
        float nv = noise[(size_t)row * NPTS + wi];
        float dclean = wk - 1e-6f * nv;
        out[OFF_KNN + row * NNB + s] = dclean;
        featsS[w][8 + s] = dclean;
      }
    }
    if (l < 8) featsS[w][l] = out[OFF_ASSIGN + row * KC + l];
    if (l >= 13 && l < 16) featsS[w][l] = out[OFF_STATS + row * 3 + (l - 13)];
    __syncthreads();
    float h = b1s[l];
#pragma unroll
    for (int i = 0; i < 16; i++) h = fmaf(featsS[w][i], w1s[i * 64 + l], h);
    hS[w][l] = fmaxf(h, 0.f);
    __syncthreads();
    if (l < 32) {
      float e = b2s[l];
#pragma unroll
      for (int i = 0; i < 64; i++) e = fmaf(hS[w][i], w2s[i * 32 + l], e);
      out[OFF_ENC + row * 32 + l] = e;
    }
    __syncthreads();
  }
}

extern "C" void kernel_launch(void* const* d_in, const int* in_sizes, int n_in,
                              void* d_out, int out_size, void* d_ws, size_t ws_size,
                              hipStream_t stream) {
  const float* x     = (const float*)d_in[0];
  const float* noise = (const float*)d_in[1];
  const float* cc    = (const float*)d_in[2];
  const float* w1    = (const float*)d_in[3];
  const float* b1    = (const float*)d_in[4];
  const float* w2    = (const float*)d_in[5];
  const float* b2    = (const float*)d_in[6];
  const float* temp  = (const float*)d_in[7];
  const float* cw    = (const float*)d_in[8];
  float* out = (float*)d_out;
  float* ws  = (float*)d_ws;

  const size_t need = XB_OFF + (size_t)NPTS * DIM * 2;  // 12.4 MB
  const bool fast = ws_size >= need;

  hipLaunchKernelGGL(k_init,  dim3(1),   dim3(64),  0, stream, cc, ws);
  hipLaunchKernelGGL(k_stats, dim3(512), dim3(256), 0, stream, x, cc, temp, cw, out, ws);
  hipLaunchKernelGGL(k_final, dim3(1),   dim3(256), 0, stream, out, ws);
  if (fast) {
    unsigned short* xp = (unsigned short*)((char*)d_ws + XB_OFF);
    hipLaunchKernelGGL(k_pack,  dim3(2048), dim3(256), 0, stream, x, xp);
    hipLaunchKernelGGL(k_gemm5, dim3(256),  dim3(512), 0, stream, xp, ws);
    hipLaunchKernelGGL(k_merge, dim3(256),  dim3(256), 0, stream, noise, w1, b1, w2, b2, out, ws, 20, 1);
  } else {
    hipLaunchKernelGGL(k_gemm,  dim3(64, 8), dim3(256), 0, stream, x, noise, ws);
    hipLaunchKernelGGL(k_merge, dim3(256),  dim3(256), 0, stream, noise, w1, b1, w2, b2, out, ws, 40, 0);
  }
}